// Round 16
// baseline (200.632 us; speedup 1.0000x reference)
//
#include <hip/hip_runtime.h>
#include <hip/hip_cooperative_groups.h>
#include <math.h>

namespace cg = cooperative_groups;

#define B 128
#define N 2048
#define D 256
#define K 64
#define CHN 4           // windows per batch
#define RPW (N / CHN)   // rows per window = 512
#define MASKED_KEY 0x007FFFFFu   // = map(-inf); strictly below every finite-score key

typedef unsigned long long u64;

// ---------------- workspace layout (in floats) ----------------
#define OFF_Q       0                          // B*D
#define OFF_V       (OFF_Q + B * D)            // B*D
#define OFF_C2      (OFF_V + B * D)            // B
#define OFF_CNT     (OFF_C2 + B)               // B*CHN ints
#define OFF_PART    (OFF_CNT + B * CHN)        // B*CHN*D
#define OFF_LISTS   (OFF_PART + B * CHN * D)   // B*CHN*K u64 (offsets even -> 8B aligned)

// ---------------- output layout (in floats) ----------------
#define O_TOK   0                      // B*K*D
#define O_MASK  (O_TOK + B * K * D)    // B*K
#define O_IDX   (O_MASK + B * K)       // B*K
#define O_IMP   (O_IDX + B * K)        // B*K
#define O_GLOB  (O_IMP + B * K)        // B*D

__device__ __forceinline__ bool mask_at(const void* p, int mode, int i) {
    if (mode == 1) return ((const unsigned char*)p)[i] != 0;
    if (mode == 2) return ((const float*)p)[i] != 0.0f;
    return ((const int*)p)[i] != 0;
}

// Full bitonic sort, descending across 64 lanes (by u64 value).
__device__ __forceinline__ u64 wave_sort_desc(u64 P, int l) {
    #pragma unroll
    for (int k2 = 2; k2 <= 64; k2 <<= 1) {
        #pragma unroll
        for (int j = k2 >> 1; j >= 1; j >>= 1) {
            u64 o = __shfl_xor(P, j, 64);
            bool lower = (l & j) == 0;
            bool descB = (l & k2) == 0;
            bool og = o > P;
            if (og == (lower == descB)) P = o;
        }
    }
    return P;
}

// Bitonic merge, descending (input bitonic), whole wave.
__device__ __forceinline__ u64 wave_merge_desc(u64 P, int l) {
    #pragma unroll
    for (int j = 32; j >= 1; j >>= 1) {
        u64 o = __shfl_xor(P, j, 64);
        bool lower = (l & j) == 0;
        bool og = o > P;
        if (og == lower) P = o;
    }
    return P;
}

// One cooperative kernel, 4 phases separated by grid.sync().
// Grid = B*CHN = 512 blocks; only 2 blocks/CU co-residency required.
__global__ __launch_bounds__(256, 2) void fused_kernel(
        const float* __restrict__ latent, const void* __restrict__ maskp,
        const float* __restrict__ Wq, const float* __restrict__ bq,
        const float* __restrict__ Wk, const float* __restrict__ bk,
        const float* __restrict__ Ws, const float* __restrict__ bs,
        float* __restrict__ qbuf, float* __restrict__ v, float* __restrict__ c2,
        int* __restrict__ cntpart, float* __restrict__ partials,
        u64* __restrict__ lists,
        float* __restrict__ out_mask, float* __restrict__ out_idx,
        float* __restrict__ out_imp, float* __restrict__ out_tok,
        float* __restrict__ out_glob) {
    cg::grid_group grid = cg::this_grid();
    int blk = blockIdx.x;
    int b = blk >> 2, s = blk & 3;
    int t = threadIdx.x, w = t >> 6, l = t & 63;
    int g = l >> 4, i = l & 15;

    __shared__ float red[16][D];      // 16 KB scratch (phases B/C/D overlays)
    __shared__ u64 cand[RPW];         // 4 KB
    __shared__ int rlds[RPW];         // 2 KB
    __shared__ u64 lb[CHN * K];       // 2 KB
    __shared__ int sortedIdx[K];
    __shared__ float ego[D];          // 1 KB
    __shared__ float c2part[4];
    __shared__ int smode;
    __shared__ unsigned long long bal[8];
    __shared__ int s_M;
    __shared__ float s_cnt;

    // mode detect (every block, reads first 4KB of mask)
    if (w == 0) {
        const unsigned int* mw = (const unsigned int*)maskp;
        bool isF = false, hasHigh = false;
        for (int k = 0; k < 16; ++k) {
            unsigned int x = mw[l * 16 + k];
            if (x == 0x3F800000u) isF = true;
            if (x & 0xFFFFFF00u) hasHigh = true;
        }
        unsigned long long bf = __ballot(isF);
        unsigned long long bh = __ballot(hasHigh);
        if (l == 0) smode = bf ? 2 : (bh ? 1 : 0);
    }
    ego[t] = latent[(size_t)b * N * D + t];
    __syncthreads();
    int mode = smode;

    // ---------------- Phase A: q rows [s*64, s*64+64) ----------------
    {
        const float4* e4 = (const float4*)ego;
        float4 ev0 = e4[i], ev1 = e4[i + 16], ev2 = e4[i + 32], ev3 = e4[i + 48];
        #pragma unroll
        for (int it = 0; it < 4; ++it) {
            int r = s * 64 + w * 16 + it * 4 + g;
            const float4* row = (const float4*)(Wq + (size_t)r * D);
            float4 x0 = row[i], x1 = row[i + 16], x2 = row[i + 32], x3 = row[i + 48];
            float p = x0.x * ev0.x;
            p = fmaf(x0.y, ev0.y, p); p = fmaf(x0.z, ev0.z, p); p = fmaf(x0.w, ev0.w, p);
            p = fmaf(x1.x, ev1.x, p); p = fmaf(x1.y, ev1.y, p);
            p = fmaf(x1.z, ev1.z, p); p = fmaf(x1.w, ev1.w, p);
            p = fmaf(x2.x, ev2.x, p); p = fmaf(x2.y, ev2.y, p);
            p = fmaf(x2.z, ev2.z, p); p = fmaf(x2.w, ev2.w, p);
            p = fmaf(x3.x, ev3.x, p); p = fmaf(x3.y, ev3.y, p);
            p = fmaf(x3.z, ev3.z, p); p = fmaf(x3.w, ev3.w, p);
            #pragma unroll
            for (int m = 8; m >= 1; m >>= 1) p += __shfl_xor(p, m, 64);
            if (i == 0) qbuf[b * D + r] = p + bq[r];
        }
    }
    grid.sync();

    // ---------------- Phase B: v cols [s*64, s*64+64); c2 on s==0 ----------------
    {
        float (*redB)[64] = (float(*)[64])red;
        int c = s * 64 + (t & 63);
        int e0 = (t >> 6) * 64;
        float part = 0.f;
        #pragma unroll 16
        for (int e = e0; e < e0 + 64; ++e)
            part = fmaf(qbuf[b * D + e], Wk[(size_t)e * D + c], part);
        redB[t >> 6][t & 63] = part;
        if (s == 0) {
            float pc = qbuf[b * D + t] * bk[t];
            #pragma unroll
            for (int m = 32; m >= 1; m >>= 1) pc += __shfl_xor(pc, m, 64);
            if (l == 0) c2part[w] = pc;
        }
        __syncthreads();
        if (t < 64) {
            float sv = redB[0][t] + redB[1][t] + redB[2][t] + redB[3][t];
            v[b * D + s * 64 + t] = sv * 0.0625f + Ws[s * 64 + t];
        }
        if (s == 0 && t == 0)
            c2[b] = (c2part[0] + c2part[1] + c2part[2] + c2part[3]) * 0.0625f + bs[0];
    }
    grid.sync();

    // ---------------- Phase C: streaming over window [s*RPW, (s+1)*RPW) ----------------
    int base = s * RPW;
    bool m0, m1;
    {
        m0 = mask_at(maskp, mode, b * N + base + t);
        m1 = mask_at(maskp, mode, b * N + base + 256 + t);
        unsigned long long b0 = __ballot(m0);
        unsigned long long b1 = __ballot(m1);
        if (l == 0) { bal[w] = b0; bal[4 + w] = b1; }
        cand[t] = ((u64)MASKED_KEY << 16);
        cand[256 + t] = ((u64)MASKED_KEY << 16);
        __syncthreads();
        int pre[8];
        int run = 0;
        #pragma unroll
        for (int q2 = 0; q2 < 8; ++q2) { pre[q2] = run; run += (int)__popcll(bal[q2]); }
        if (m0) rlds[pre[w] + (int)__popcll(bal[w] & ((1ull << l) - 1ull))] = base + t;
        if (m1) rlds[pre[4 + w] + (int)__popcll(bal[4 + w] & ((1ull << l) - 1ull))] = base + 256 + t;
        if (t == 0) { s_M = run; cntpart[b * CHN + s] = run; }
    }
    const float4* v4 = (const float4*)(v + b * D);
    float4 vv0 = v4[i], vv1 = v4[i + 16], vv2 = v4[i + 32], vv3 = v4[i + 48];
    float c2b = c2[b];
    float ax0=0,ay0=0,az0=0,aw0=0, ax1=0,ay1=0,az1=0,aw1=0;
    float ax2=0,ay2=0,az2=0,aw2=0, ax3=0,ay3=0,az3=0,aw3=0;
    const float4* lat4 = (const float4*)(latent + (size_t)b * N * D);
    __syncthreads();
    int M = s_M;

    #pragma unroll 2
    for (int jj = w * 4 + g; jj < M; jj += 16) {
        int n = rlds[jj];
        const float4* row = lat4 + (size_t)n * (D / 4);
        float4 x0 = row[i], x1 = row[i + 16], x2 = row[i + 32], x3 = row[i + 48];
        float p = x0.x * vv0.x;
        p = fmaf(x0.y, vv0.y, p); p = fmaf(x0.z, vv0.z, p); p = fmaf(x0.w, vv0.w, p);
        p = fmaf(x1.x, vv1.x, p); p = fmaf(x1.y, vv1.y, p);
        p = fmaf(x1.z, vv1.z, p); p = fmaf(x1.w, vv1.w, p);
        p = fmaf(x2.x, vv2.x, p); p = fmaf(x2.y, vv2.y, p);
        p = fmaf(x2.z, vv2.z, p); p = fmaf(x2.w, vv2.w, p);
        p = fmaf(x3.x, vv3.x, p); p = fmaf(x3.y, vv3.y, p);
        p = fmaf(x3.z, vv3.z, p); p = fmaf(x3.w, vv3.w, p);
        #pragma unroll
        for (int m = 8; m >= 1; m >>= 1) p += __shfl_xor(p, m, 64);  // 16-lane reduce
        if (i == 0) {
            unsigned int fu = __float_as_uint(p + c2b);
            unsigned int ky = (fu & 0x80000000u) ? ~fu : (fu | 0x80000000u);
            cand[jj] = ((u64)ky << 16) | (u64)(2047 - n);
        }
        ax0 += x0.x; ay0 += x0.y; az0 += x0.z; aw0 += x0.w;
        ax1 += x1.x; ay1 += x1.y; az1 += x1.z; aw1 += x1.w;
        ax2 += x2.x; ay2 += x2.y; az2 += x2.z; aw2 += x2.w;
        ax3 += x3.x; ay3 += x3.y; az3 += x3.z; aw3 += x3.w;
    }
    {
        float* rr = red[w * 4 + g];
        rr[i*4+0]=ax0; rr[i*4+1]=ay0; rr[i*4+2]=az0; rr[i*4+3]=aw0;
        rr[64+i*4+0]=ax1; rr[64+i*4+1]=ay1; rr[64+i*4+2]=az1; rr[64+i*4+3]=aw1;
        rr[128+i*4+0]=ax2; rr[128+i*4+1]=ay2; rr[128+i*4+2]=az2; rr[128+i*4+3]=aw2;
        rr[192+i*4+0]=ax3; rr[192+i*4+1]=ay3; rr[192+i*4+2]=az3; rr[192+i*4+3]=aw3;
        __syncthreads();
        float sm = 0.f;
        #pragma unroll
        for (int r = 0; r < 16; ++r) sm += red[r][t];
        partials[((size_t)b * CHN + s) * D + t] = sm;
    }
    // wave 0: sorted top-64 of this window's <=512 candidates (8 chunks)
    if (w == 0) {
        u64 A = wave_sort_desc(cand[l], l);
        #pragma unroll
        for (int q = 1; q < 8; ++q) {
            u64 Bc = wave_sort_desc(cand[q * 64 + l], l);
            u64 rev = __shfl_xor(Bc, 63, 64);
            A = (A > rev) ? A : rev;
            A = wave_merge_desc(A, l);
        }
        lists[((size_t)b * CHN + s) * K + l] = A;
    }
    grid.sync();

    // ---------------- Phase D: merge (redundant per block) + outputs ----------------
    if (t < CHN * K) lb[t] = lists[(size_t)b * CHN * K + t];
    if (t == 0) {
        int ct = 0;
        #pragma unroll
        for (int q = 0; q < CHN; ++q) ct += cntpart[b * CHN + q];
        s_cnt = (float)ct;
    }
    __syncthreads();

    if (w == 0) {
        u64 cur = lb[l];
        #pragma unroll
        for (int q = 1; q < CHN; ++q) {
            u64 rev = lb[q * K + (63 - l)];
            cur = (cur > rev) ? cur : rev;
            cur = wave_merge_desc(cur, l);
        }
        unsigned int u = (unsigned int)(cur >> 16);
        int pos = 2047 - (int)(cur & 0xFFFFu);
        sortedIdx[l] = pos;
        if (s == 0) {
            unsigned int fu = (u & 0x80000000u) ? (u ^ 0x80000000u) : ~u;
            float selv = __uint_as_float(fu);
            bool m = (u != MASKED_KEY);
            float x = m ? selv : -1e9f;
            float mx = x;
            #pragma unroll
            for (int mm = 1; mm <= 32; mm <<= 1) mx = fmaxf(mx, __shfl_xor(mx, mm, 64));
            float e = expf(x - mx);
            float sm = e;
            #pragma unroll
            for (int mm = 1; mm <= 32; mm <<= 1) sm += __shfl_xor(sm, mm, 64);
            out_idx[b * K + l] = (float)pos;
            out_mask[b * K + l] = m ? 1.f : 0.f;
            out_imp[b * K + l] = e / sm;
        }
    }
    __syncthreads();

    // gather: this block handles rows [s*16, s*16+16), 4 rows per wave
    #pragma unroll
    for (int rr2 = 0; rr2 < 4; ++rr2) {
        int r = s * 16 + w * 4 + rr2;
        int idx = sortedIdx[r];
        float4 x = ((const float4*)(latent + ((size_t)b * N + idx) * D))[l];
        ((float4*)(out_tok + ((size_t)b * K + r) * D))[l] = x;
    }
    // colsum finalize: cols [s*64, s*64+64)
    {
        float (*redB)[64] = (float(*)[64])red;
        float pv = partials[((size_t)b * CHN + (t >> 6)) * D + s * 64 + (t & 63)];
        __syncthreads();
        redB[t >> 6][t & 63] = pv;
        __syncthreads();
        if (t < 64) {
            float sv = redB[0][t] + redB[1][t] + redB[2][t] + redB[3][t];
            out_glob[b * D + s * 64 + t] = sv / s_cnt;
        }
    }
}

extern "C" void kernel_launch(void* const* d_in, const int* in_sizes, int n_in,
                              void* d_out, int out_size, void* d_ws, size_t ws_size,
                              hipStream_t stream) {
    const float* latent = (const float*)d_in[0];
    const void*  maskp  = d_in[1];
    const float* Wq = (const float*)d_in[2];
    const float* bq = (const float*)d_in[3];
    const float* Wk = (const float*)d_in[4];
    const float* bk = (const float*)d_in[5];
    const float* Ws = (const float*)d_in[6];
    const float* bs = (const float*)d_in[7];

    float* ws = (float*)d_ws;
    float* qbuf   = ws + OFF_Q;
    float* v      = ws + OFF_V;
    float* c2     = ws + OFF_C2;
    int*   cntp   = (int*)(ws + OFF_CNT);
    float* part   = ws + OFF_PART;
    u64*   lists  = (u64*)(ws + OFF_LISTS);
    float* out = (float*)d_out;
    float* om = out + O_MASK;
    float* oi = out + O_IDX;
    float* oim = out + O_IMP;
    float* ot = out + O_TOK;
    float* og = out + O_GLOB;

    void* args[] = {
        (void*)&latent, (void*)&maskp, (void*)&Wq, (void*)&bq, (void*)&Wk,
        (void*)&bk, (void*)&Ws, (void*)&bs, (void*)&qbuf, (void*)&v,
        (void*)&c2, (void*)&cntp, (void*)&part, (void*)&lists,
        (void*)&om, (void*)&oi, (void*)&oim, (void*)&ot, (void*)&og
    };
    hipLaunchCooperativeKernel((const void*)fused_kernel, dim3(B * CHN), dim3(256),
                               args, 0, stream);
}

// Round 17
// 97.720 us; speedup vs baseline: 2.0531x; 2.0531x over previous
//
#include <hip/hip_runtime.h>
#include <math.h>

#define B 128
#define N 2048
#define D 256
#define K 64
#define CH 16          // chunks per batch in main kernel
#define RPC (N / CH)   // rows per chunk = 128
#define MASKED_KEY 0x007FFFFFu   // = map(-inf); strictly below every finite-score key

typedef unsigned long long u64;

// ---------------- workspace layout (in floats) ----------------
#define OFF_V       0                          // B*D
#define OFF_C2      (OFF_V + B * D)            // B
#define OFF_CNT     (OFF_C2 + B)               // B
#define OFF_PART    (OFF_CNT + B)              // B*CH*D
#define OFF_MODE    (OFF_PART + B * CH * D)    // 64 (aligned pad)
#define OFF_LISTS   (OFF_MODE + 64)            // B*CH*K u64 (8B-aligned)

// ---------------- output layout (in floats) ----------------
#define O_TOK   0                      // B*K*D
#define O_MASK  (O_TOK + B * K * D)    // B*K
#define O_IDX   (O_MASK + B * K)       // B*K
#define O_IMP   (O_IDX + B * K)        // B*K
#define O_GLOB  (O_IMP + B * K)        // B*D

__device__ __forceinline__ bool mask_at(const void* p, int mode, int i) {
    if (mode == 1) return ((const unsigned char*)p)[i] != 0;
    if (mode == 2) return ((const float*)p)[i] != 0.0f;
    return ((const int*)p)[i] != 0;
}

// Full bitonic sort, descending across 64 lanes (by u64 value).
__device__ __forceinline__ u64 wave_sort_desc(u64 P, int l) {
    #pragma unroll
    for (int k2 = 2; k2 <= 64; k2 <<= 1) {
        #pragma unroll
        for (int j = k2 >> 1; j >= 1; j >>= 1) {
            u64 o = __shfl_xor(P, j, 64);
            bool lower = (l & j) == 0;
            bool descB = (l & k2) == 0;
            bool og = o > P;
            if (og == (lower == descB)) P = o;
        }
    }
    return P;
}

// Bitonic merge, descending (input bitonic), whole wave.
__device__ __forceinline__ u64 wave_merge_desc(u64 P, int l) {
    #pragma unroll
    for (int j = 32; j >= 1; j >>= 1) {
        u64 o = __shfl_xor(P, j, 64);
        bool lower = (l & j) == 0;
        bool og = o > P;
        if (og == lower) P = o;
    }
    return P;
}

// Fused per-batch prep: mode-detect; q = Wq@ego + bq (16-lane/row groups);
// v = (q^T Wk)/16 + Ws (coalesced sweep); c2 = (q.bk)/16 + bs; cnt = sum(mask).
__global__ __launch_bounds__(256) void prep_kernel(
        const float* __restrict__ latent, const void* __restrict__ maskp,
        const float* __restrict__ Wq, const float* __restrict__ bq,
        const float* __restrict__ Wk, const float* __restrict__ bk,
        const float* __restrict__ Ws, const float* __restrict__ bs,
        float* __restrict__ v, float* __restrict__ c2, float* __restrict__ cnt,
        int* __restrict__ modep) {
    int b = blockIdx.x, t = threadIdx.x, w = t >> 6, l = t & 63;
    int g = l >> 4, i = l & 15;
    __shared__ float ego[D];
    __shared__ float q[D];
    __shared__ int smode;
    if (w == 0) {
        const unsigned int* mw = (const unsigned int*)maskp;
        bool isF = false, hasHigh = false;
        for (int k = 0; k < 16; ++k) {
            unsigned int x = mw[l * 16 + k];
            if (x == 0x3F800000u) isF = true;
            if (x & 0xFFFFFF00u) hasHigh = true;
        }
        unsigned long long bf = __ballot(isF);
        unsigned long long bh = __ballot(hasHigh);
        if (l == 0) smode = bf ? 2 : (bh ? 1 : 0);
    }
    ego[t] = latent[(size_t)b * N * D + t];
    __syncthreads();
    int mode = smode;
    if (b == 0 && t == 0) *modep = mode;

    // stage 1: q[r] = Wq[r,:].ego + bq[r] -- 16 lanes/row, 4 rows/wave/iter
    const float4* e4 = (const float4*)ego;
    float4 ev0 = e4[i], ev1 = e4[i + 16], ev2 = e4[i + 32], ev3 = e4[i + 48];
    for (int it = 0; it < 16; ++it) {
        int r = w * 64 + it * 4 + g;
        const float4* row = (const float4*)(Wq + (size_t)r * D);
        float4 x0 = row[i], x1 = row[i + 16], x2 = row[i + 32], x3 = row[i + 48];
        float p = x0.x * ev0.x;
        p = fmaf(x0.y, ev0.y, p); p = fmaf(x0.z, ev0.z, p); p = fmaf(x0.w, ev0.w, p);
        p = fmaf(x1.x, ev1.x, p); p = fmaf(x1.y, ev1.y, p);
        p = fmaf(x1.z, ev1.z, p); p = fmaf(x1.w, ev1.w, p);
        p = fmaf(x2.x, ev2.x, p); p = fmaf(x2.y, ev2.y, p);
        p = fmaf(x2.z, ev2.z, p); p = fmaf(x2.w, ev2.w, p);
        p = fmaf(x3.x, ev3.x, p); p = fmaf(x3.y, ev3.y, p);
        p = fmaf(x3.z, ev3.z, p); p = fmaf(x3.w, ev3.w, p);
        #pragma unroll
        for (int m = 8; m >= 1; m >>= 1) p += __shfl_xor(p, m, 64);
        if (i == 0) q[r] = p + bq[r];
    }
    __syncthreads();

    // stage 2: v[t] = (sum_e q[e]*Wk[e,t])/16 + Ws[t] -- coalesced column sweep
    float acc = 0.f;
    #pragma unroll 16
    for (int e = 0; e < D; ++e) acc = fmaf(q[e], Wk[(size_t)e * D + t], acc);
    v[b * D + t] = acc * 0.0625f + Ws[t];

    if (t < 64) {
        float p = 0.f;
        #pragma unroll
        for (int j = 0; j < 4; ++j) p = fmaf(q[t + 64 * j], bk[t + 64 * j], p);
        #pragma unroll
        for (int m = 32; m >= 1; m >>= 1) p += __shfl_xor(p, m, 64);
        if (t == 0) c2[b] = p * 0.0625f + bs[0];
    }
    int local = 0;
    for (int k = 0; k < N / D; ++k) local += mask_at(maskp, mode, b * N + t + D * k) ? 1 : 0;
    __shared__ int ctot;
    if (t == 0) ctot = 0;
    __syncthreads();
    atomicAdd(&ctot, local);
    __syncthreads();
    if (t == 0) cnt[b] = (float)ctot;
}

// Streaming pass over masked rows of this block's fixed 128-row window
// (local ballot compaction). Plain float4 loads. Produces partial colsums +
// a SORTED per-chunk top-64 list (u64 = key<<16 | (2047-pos)).
__global__ __launch_bounds__(256) void main_kernel(
        const float* __restrict__ latent, const void* __restrict__ maskp,
        const int* __restrict__ modep,
        const float* __restrict__ v, const float* __restrict__ c2,
        float* __restrict__ partials, u64* __restrict__ lists) {
    int b = blockIdx.y, ch = blockIdx.x;
    int t = threadIdx.x, w = t >> 6, l = t & 63;
    int g = l >> 4, i = l & 15;
    __shared__ float red[16][D];     // 16 KB
    __shared__ u64 cand[RPC];        // 1 KB
    __shared__ int rlds[RPC];        // 512 B
    __shared__ unsigned long long bal[2];
    __shared__ int s_M;

    int mode = *modep;
    int base = ch * RPC;
    if (t < RPC) cand[t] = ((u64)MASKED_KEY << 16);   // pad: below all finite keys
    if (t < RPC) {                                    // waves 0,1 fully active
        bool m = mask_at(maskp, mode, b * N + base + t);
        unsigned long long bb = __ballot(m);
        if (l == 0) bal[t >> 6] = bb;
    }
    const float4* v4 = (const float4*)(v + b * D);
    float4 vv0 = v4[i], vv1 = v4[i + 16], vv2 = v4[i + 32], vv3 = v4[i + 48];
    float c2b = c2[b];
    __syncthreads();
    if (t < RPC) {
        unsigned long long bb = bal[t >> 6];
        bool m = (bb >> l) & 1ull;
        int off = ((t >> 6) ? (int)__popcll(bal[0]) : 0)
                + (int)__popcll(bb & ((1ull << l) - 1ull));
        if (m) rlds[off] = base + t;
    }
    if (t == 0) s_M = (int)(__popcll(bal[0]) + __popcll(bal[1]));
    float ax0=0,ay0=0,az0=0,aw0=0, ax1=0,ay1=0,az1=0,aw1=0;
    float ax2=0,ay2=0,az2=0,aw2=0, ax3=0,ay3=0,az3=0,aw3=0;
    const float4* lat4 = (const float4*)(latent + (size_t)b * N * D);
    __syncthreads();
    int M = s_M;

    #pragma unroll 2
    for (int jj = w * 4 + g; jj < M; jj += 16) {
        int n = rlds[jj];
        const float4* row = lat4 + (size_t)n * (D / 4);
        float4 x0 = row[i], x1 = row[i + 16], x2 = row[i + 32], x3 = row[i + 48];
        float p = x0.x * vv0.x;
        p = fmaf(x0.y, vv0.y, p); p = fmaf(x0.z, vv0.z, p); p = fmaf(x0.w, vv0.w, p);
        p = fmaf(x1.x, vv1.x, p); p = fmaf(x1.y, vv1.y, p);
        p = fmaf(x1.z, vv1.z, p); p = fmaf(x1.w, vv1.w, p);
        p = fmaf(x2.x, vv2.x, p); p = fmaf(x2.y, vv2.y, p);
        p = fmaf(x2.z, vv2.z, p); p = fmaf(x2.w, vv2.w, p);
        p = fmaf(x3.x, vv3.x, p); p = fmaf(x3.y, vv3.y, p);
        p = fmaf(x3.z, vv3.z, p); p = fmaf(x3.w, vv3.w, p);
        #pragma unroll
        for (int m = 8; m >= 1; m >>= 1) p += __shfl_xor(p, m, 64);  // 16-lane reduce
        if (i == 0) {
            unsigned int fu = __float_as_uint(p + c2b);
            unsigned int ky = (fu & 0x80000000u) ? ~fu : (fu | 0x80000000u);
            cand[jj] = ((u64)ky << 16) | (u64)(2047 - n);
        }
        ax0 += x0.x; ay0 += x0.y; az0 += x0.z; aw0 += x0.w;
        ax1 += x1.x; ay1 += x1.y; az1 += x1.z; aw1 += x1.w;
        ax2 += x2.x; ay2 += x2.y; az2 += x2.z; aw2 += x2.w;
        ax3 += x3.x; ay3 += x3.y; az3 += x3.z; aw3 += x3.w;
    }
    float* rr = red[w * 4 + g];
    rr[i*4+0]=ax0; rr[i*4+1]=ay0; rr[i*4+2]=az0; rr[i*4+3]=aw0;
    rr[64+i*4+0]=ax1; rr[64+i*4+1]=ay1; rr[64+i*4+2]=az1; rr[64+i*4+3]=aw1;
    rr[128+i*4+0]=ax2; rr[128+i*4+1]=ay2; rr[128+i*4+2]=az2; rr[128+i*4+3]=aw2;
    rr[192+i*4+0]=ax3; rr[192+i*4+1]=ay3; rr[192+i*4+2]=az3; rr[192+i*4+3]=aw3;
    __syncthreads();
    float s = 0.f;
    #pragma unroll
    for (int r = 0; r < 16; ++r) s += red[r][t];
    partials[((size_t)b * CH + ch) * D + t] = s;

    // wave 0: sorted top-64 of this chunk's <=128 candidates
    if (w == 0) {
        u64 A = wave_sort_desc(cand[l], l);
        u64 Bc = wave_sort_desc(cand[64 + l], l);
        u64 rev = __shfl_xor(Bc, 63, 64);
        A = (A > rev) ? A : rev;
        A = wave_merge_desc(A, l);
        lists[((size_t)b * CH + ch) * K + l] = A;
    }
}

// Epilogue per batch: merge 16 sorted top-64 lists -> softmax -> gather ->
// global_latent.
__global__ __launch_bounds__(256) void epilogue_kernel(
        const u64* __restrict__ listsg, const float* __restrict__ latent,
        const float* __restrict__ partials, const float* __restrict__ cnt,
        float* __restrict__ out_mask, float* __restrict__ out_idx,
        float* __restrict__ out_imp, float* __restrict__ out_tok,
        float* __restrict__ out_glob) {
    int b = blockIdx.x, t = threadIdx.x, w = t >> 6, l = t & 63;
    __shared__ u64 lb[CH * K];       // 8 KB
    __shared__ int sortedIdx[K];

    for (int q = 0; q < CH * K / 256; ++q)
        lb[t + 256 * q] = listsg[(size_t)b * CH * K + t + 256 * q];
    __syncthreads();

    if (w == 0) {
        u64 cur = lb[l];
        #pragma unroll
        for (int q = 1; q < CH; ++q) {
            u64 rev = lb[q * K + (63 - l)];
            cur = (cur > rev) ? cur : rev;
            cur = wave_merge_desc(cur, l);
        }
        unsigned int u = (unsigned int)(cur >> 16);
        int pos = 2047 - (int)(cur & 0xFFFFu);
        unsigned int fu = (u & 0x80000000u) ? (u ^ 0x80000000u) : ~u;
        float selv = __uint_as_float(fu);
        bool m = (u != MASKED_KEY);
        float x = m ? selv : -1e9f;
        float mx = x;
        #pragma unroll
        for (int mm = 1; mm <= 32; mm <<= 1) mx = fmaxf(mx, __shfl_xor(mx, mm, 64));
        float e = expf(x - mx);
        float sm = e;
        #pragma unroll
        for (int mm = 1; mm <= 32; mm <<= 1) sm += __shfl_xor(sm, mm, 64);
        out_idx[b * K + l] = (float)pos;
        out_mask[b * K + l] = m ? 1.f : 0.f;
        out_imp[b * K + l] = e / sm;
        sortedIdx[l] = pos;
    }
    __syncthreads();

    for (int r = w; r < K; r += 4) {
        int idx = sortedIdx[r];
        float4 x = ((const float4*)(latent + ((size_t)b * N + idx) * D))[l];
        ((float4*)(out_tok + ((size_t)b * K + r) * D))[l] = x;
    }
    float gs = 0.f;
    #pragma unroll
    for (int c = 0; c < CH; ++c) gs += partials[((size_t)b * CH + c) * D + t];
    out_glob[b * D + t] = gs / cnt[b];
}

extern "C" void kernel_launch(void* const* d_in, const int* in_sizes, int n_in,
                              void* d_out, int out_size, void* d_ws, size_t ws_size,
                              hipStream_t stream) {
    const float* latent = (const float*)d_in[0];
    const void*  maskp  = d_in[1];
    const float* Wq = (const float*)d_in[2];
    const float* bq = (const float*)d_in[3];
    const float* Wk = (const float*)d_in[4];
    const float* bk = (const float*)d_in[5];
    const float* Ws = (const float*)d_in[6];
    const float* bs = (const float*)d_in[7];

    float* ws = (float*)d_ws;
    float* v      = ws + OFF_V;
    float* c2     = ws + OFF_C2;
    float* cnt    = ws + OFF_CNT;
    float* part   = ws + OFF_PART;
    int*   modep  = (int*)(ws + OFF_MODE);
    u64*   lists  = (u64*)(ws + OFF_LISTS);
    float* out = (float*)d_out;

    // ---- PROBE: prep and epilogue each launched twice (idempotent).
    // dur - 72.5 = prep_marginal + epilogue_marginal.
    hipLaunchKernelGGL(prep_kernel, dim3(B), dim3(256), 0, stream,
                       latent, maskp, Wq, bq, Wk, bk, Ws, bs, v, c2, cnt, modep);
    hipLaunchKernelGGL(prep_kernel, dim3(B), dim3(256), 0, stream,
                       latent, maskp, Wq, bq, Wk, bk, Ws, bs, v, c2, cnt, modep);
    hipLaunchKernelGGL(main_kernel, dim3(CH, B), dim3(256), 0, stream,
                       latent, maskp, modep, v, c2, part, lists);
    hipLaunchKernelGGL(epilogue_kernel, dim3(B), dim3(256), 0, stream,
                       lists, latent, part, cnt,
                       out + O_MASK, out + O_IDX, out + O_IMP, out + O_TOK, out + O_GLOB);
    hipLaunchKernelGGL(epilogue_kernel, dim3(B), dim3(256), 0, stream,
                       lists, latent, part, cnt,
                       out + O_MASK, out + O_IDX, out + O_IMP, out + O_TOK, out + O_GLOB);
}

// Round 18
// 61.551 us; speedup vs baseline: 3.2596x; 1.5876x over previous
//
#include <hip/hip_runtime.h>
#include <math.h>

#define B 128
#define N 2048
#define D 256
#define K 64
#define CH 16          // chunks per batch in main kernel
#define RPC (N / CH)   // rows per chunk = 128
#define MASKED_KEY 0x007FFFFFu   // = map(-inf); strictly below every finite-score key

typedef unsigned long long u64;

// ---------------- workspace layout (in floats) ----------------
#define OFF_V       0                          // B*D
#define OFF_C2      (OFF_V + B * D)            // B
#define OFF_CNT     (OFF_C2 + B)               // B
#define OFF_PART    (OFF_CNT + B)              // B*CH*D
#define OFF_MODE    (OFF_PART + B * CH * D)    // 64 (aligned pad)
#define OFF_LISTS   (OFF_MODE + 64)            // B*CH*K u64 (8B-aligned)

// ---------------- output layout (in floats) ----------------
#define O_TOK   0                      // B*K*D
#define O_MASK  (O_TOK + B * K * D)    // B*K
#define O_IDX   (O_MASK + B * K)       // B*K
#define O_IMP   (O_IDX + B * K)        // B*K
#define O_GLOB  (O_IMP + B * K)        // B*D

__device__ __forceinline__ bool mask_at(const void* p, int mode, int i) {
    if (mode == 1) return ((const unsigned char*)p)[i] != 0;
    if (mode == 2) return ((const float*)p)[i] != 0.0f;
    return ((const int*)p)[i] != 0;
}

// Full bitonic sort, descending across 64 lanes (by u64 value).
__device__ __forceinline__ u64 wave_sort_desc(u64 P, int l) {
    #pragma unroll
    for (int k2 = 2; k2 <= 64; k2 <<= 1) {
        #pragma unroll
        for (int j = k2 >> 1; j >= 1; j >>= 1) {
            u64 o = __shfl_xor(P, j, 64);
            bool lower = (l & j) == 0;
            bool descB = (l & k2) == 0;
            bool og = o > P;
            if (og == (lower == descB)) P = o;
        }
    }
    return P;
}

// Bitonic merge, descending (input bitonic), whole wave.
__device__ __forceinline__ u64 wave_merge_desc(u64 P, int l) {
    #pragma unroll
    for (int j = 32; j >= 1; j >>= 1) {
        u64 o = __shfl_xor(P, j, 64);
        bool lower = (l & j) == 0;
        bool og = o > P;
        if (og == lower) P = o;
    }
    return P;
}

// Per-batch prep, 2 blocks/batch (s=0,1): mode-detect; q = Wq@ego + bq
// (full, redundant, in-LDS); v cols [s*128,(s+1)*128) with e-range split;
// c2 on s==0; cnt on s==1.
__global__ __launch_bounds__(256) void prep_kernel(
        const float* __restrict__ latent, const void* __restrict__ maskp,
        const float* __restrict__ Wq, const float* __restrict__ bq,
        const float* __restrict__ Wk, const float* __restrict__ bk,
        const float* __restrict__ Ws, const float* __restrict__ bs,
        float* __restrict__ v, float* __restrict__ c2, float* __restrict__ cnt,
        int* __restrict__ modep) {
    int blk = blockIdx.x;
    int b = blk >> 1, s = blk & 1;
    int t = threadIdx.x, w = t >> 6, l = t & 63;
    int g = l >> 4, i = l & 15;
    __shared__ float ego[D];
    __shared__ float q[D];
    __shared__ float redp[2][128];
    __shared__ int smode;
    if (w == 0) {
        const unsigned int* mw = (const unsigned int*)maskp;
        bool isF = false, hasHigh = false;
        for (int k = 0; k < 16; ++k) {
            unsigned int x = mw[l * 16 + k];
            if (x == 0x3F800000u) isF = true;
            if (x & 0xFFFFFF00u) hasHigh = true;
        }
        unsigned long long bf = __ballot(isF);
        unsigned long long bh = __ballot(hasHigh);
        if (l == 0) smode = bf ? 2 : (bh ? 1 : 0);
    }
    ego[t] = latent[(size_t)b * N * D + t];
    __syncthreads();
    int mode = smode;
    if (blk == 0 && t == 0) *modep = mode;

    // stage 1 (redundant per block): q[r] = Wq[r,:].ego + bq[r]
    const float4* e4 = (const float4*)ego;
    float4 ev0 = e4[i], ev1 = e4[i + 16], ev2 = e4[i + 32], ev3 = e4[i + 48];
    for (int it = 0; it < 16; ++it) {
        int r = w * 64 + it * 4 + g;
        const float4* row = (const float4*)(Wq + (size_t)r * D);
        float4 x0 = row[i], x1 = row[i + 16], x2 = row[i + 32], x3 = row[i + 48];
        float p = x0.x * ev0.x;
        p = fmaf(x0.y, ev0.y, p); p = fmaf(x0.z, ev0.z, p); p = fmaf(x0.w, ev0.w, p);
        p = fmaf(x1.x, ev1.x, p); p = fmaf(x1.y, ev1.y, p);
        p = fmaf(x1.z, ev1.z, p); p = fmaf(x1.w, ev1.w, p);
        p = fmaf(x2.x, ev2.x, p); p = fmaf(x2.y, ev2.y, p);
        p = fmaf(x2.z, ev2.z, p); p = fmaf(x2.w, ev2.w, p);
        p = fmaf(x3.x, ev3.x, p); p = fmaf(x3.y, ev3.y, p);
        p = fmaf(x3.z, ev3.z, p); p = fmaf(x3.w, ev3.w, p);
        #pragma unroll
        for (int m = 8; m >= 1; m >>= 1) p += __shfl_xor(p, m, 64);
        if (i == 0) q[r] = p + bq[r];
    }
    __syncthreads();

    // stage 2: cols [s*128, s*128+128), e-range split across thread halves
    {
        int c = s * 128 + (t & 127);
        int eh = t >> 7;
        float acc = 0.f;
        #pragma unroll 16
        for (int e = eh * 128; e < eh * 128 + 128; ++e)
            acc = fmaf(q[e], Wk[(size_t)e * D + c], acc);
        redp[eh][t & 127] = acc;
    }
    // concurrent per-block extras
    if (s == 0) {
        if (t < 64) {
            float p = 0.f;
            #pragma unroll
            for (int j = 0; j < 4; ++j) p = fmaf(q[t + 64 * j], bk[t + 64 * j], p);
            #pragma unroll
            for (int m = 32; m >= 1; m >>= 1) p += __shfl_xor(p, m, 64);
            if (t == 0) c2[b] = p * 0.0625f + bs[0];
        }
    } else {
        int local = 0;
        for (int k = 0; k < N / D; ++k) local += mask_at(maskp, mode, b * N + t + D * k) ? 1 : 0;
        __shared__ int ctot;
        if (t == 0) ctot = 0;
        __syncthreads();
        atomicAdd(&ctot, local);
        __syncthreads();
        if (t == 0) cnt[b] = (float)ctot;
        __syncthreads();   // keep both branches' sync counts compatible pre-final-sync
    }
    __syncthreads();
    if (t < 128)
        v[b * D + s * 128 + t] = (redp[0][t] + redp[1][t]) * 0.0625f + Ws[s * 128 + t];
}

// Streaming pass over masked rows of this block's fixed 128-row window
// (local ballot compaction). Plain float4 loads. Produces partial colsums +
// a SORTED per-chunk top-64 list (u64 = key<<16 | (2047-pos)).
__global__ __launch_bounds__(256) void main_kernel(
        const float* __restrict__ latent, const void* __restrict__ maskp,
        const int* __restrict__ modep,
        const float* __restrict__ v, const float* __restrict__ c2,
        float* __restrict__ partials, u64* __restrict__ lists) {
    int b = blockIdx.y, ch = blockIdx.x;
    int t = threadIdx.x, w = t >> 6, l = t & 63;
    int g = l >> 4, i = l & 15;
    __shared__ float red[16][D];     // 16 KB
    __shared__ u64 cand[RPC];        // 1 KB
    __shared__ int rlds[RPC];        // 512 B
    __shared__ unsigned long long bal[2];
    __shared__ int s_M;

    int mode = *modep;
    int base = ch * RPC;
    if (t < RPC) cand[t] = ((u64)MASKED_KEY << 16);   // pad: below all finite keys
    if (t < RPC) {                                    // waves 0,1 fully active
        bool m = mask_at(maskp, mode, b * N + base + t);
        unsigned long long bb = __ballot(m);
        if (l == 0) bal[t >> 6] = bb;
    }
    const float4* v4 = (const float4*)(v + b * D);
    float4 vv0 = v4[i], vv1 = v4[i + 16], vv2 = v4[i + 32], vv3 = v4[i + 48];
    float c2b = c2[b];
    __syncthreads();
    if (t < RPC) {
        unsigned long long bb = bal[t >> 6];
        bool m = (bb >> l) & 1ull;
        int off = ((t >> 6) ? (int)__popcll(bal[0]) : 0)
                + (int)__popcll(bb & ((1ull << l) - 1ull));
        if (m) rlds[off] = base + t;
    }
    if (t == 0) s_M = (int)(__popcll(bal[0]) + __popcll(bal[1]));
    float ax0=0,ay0=0,az0=0,aw0=0, ax1=0,ay1=0,az1=0,aw1=0;
    float ax2=0,ay2=0,az2=0,aw2=0, ax3=0,ay3=0,az3=0,aw3=0;
    const float4* lat4 = (const float4*)(latent + (size_t)b * N * D);
    __syncthreads();
    int M = s_M;

    #pragma unroll 2
    for (int jj = w * 4 + g; jj < M; jj += 16) {
        int n = rlds[jj];
        const float4* row = lat4 + (size_t)n * (D / 4);
        float4 x0 = row[i], x1 = row[i + 16], x2 = row[i + 32], x3 = row[i + 48];
        float p = x0.x * vv0.x;
        p = fmaf(x0.y, vv0.y, p); p = fmaf(x0.z, vv0.z, p); p = fmaf(x0.w, vv0.w, p);
        p = fmaf(x1.x, vv1.x, p); p = fmaf(x1.y, vv1.y, p);
        p = fmaf(x1.z, vv1.z, p); p = fmaf(x1.w, vv1.w, p);
        p = fmaf(x2.x, vv2.x, p); p = fmaf(x2.y, vv2.y, p);
        p = fmaf(x2.z, vv2.z, p); p = fmaf(x2.w, vv2.w, p);
        p = fmaf(x3.x, vv3.x, p); p = fmaf(x3.y, vv3.y, p);
        p = fmaf(x3.z, vv3.z, p); p = fmaf(x3.w, vv3.w, p);
        #pragma unroll
        for (int m = 8; m >= 1; m >>= 1) p += __shfl_xor(p, m, 64);  // 16-lane reduce
        if (i == 0) {
            unsigned int fu = __float_as_uint(p + c2b);
            unsigned int ky = (fu & 0x80000000u) ? ~fu : (fu | 0x80000000u);
            cand[jj] = ((u64)ky << 16) | (u64)(2047 - n);
        }
        ax0 += x0.x; ay0 += x0.y; az0 += x0.z; aw0 += x0.w;
        ax1 += x1.x; ay1 += x1.y; az1 += x1.z; aw1 += x1.w;
        ax2 += x2.x; ay2 += x2.y; az2 += x2.z; aw2 += x2.w;
        ax3 += x3.x; ay3 += x3.y; az3 += x3.z; aw3 += x3.w;
    }
    float* rr = red[w * 4 + g];
    rr[i*4+0]=ax0; rr[i*4+1]=ay0; rr[i*4+2]=az0; rr[i*4+3]=aw0;
    rr[64+i*4+0]=ax1; rr[64+i*4+1]=ay1; rr[64+i*4+2]=az1; rr[64+i*4+3]=aw1;
    rr[128+i*4+0]=ax2; rr[128+i*4+1]=ay2; rr[128+i*4+2]=az2; rr[128+i*4+3]=aw2;
    rr[192+i*4+0]=ax3; rr[192+i*4+1]=ay3; rr[192+i*4+2]=az3; rr[192+i*4+3]=aw3;
    __syncthreads();
    float s = 0.f;
    #pragma unroll
    for (int r = 0; r < 16; ++r) s += red[r][t];
    partials[((size_t)b * CH + ch) * D + t] = s;

    // wave 0: sorted top-64 of this chunk's <=128 candidates
    if (w == 0) {
        u64 A = wave_sort_desc(cand[l], l);
        u64 Bc = wave_sort_desc(cand[64 + l], l);
        u64 rev = __shfl_xor(Bc, 63, 64);
        A = (A > rev) ? A : rev;
        A = wave_merge_desc(A, l);
        lists[((size_t)b * CH + ch) * K + l] = A;
    }
}

// Epilogue, 4 blocks/batch (s=0..3): tree-merge 16 sorted lists (4 waves x 4
// lists, then wave 0 x 4) -> softmax (s==0) -> gather rows [s*16,s*16+16) ->
// colsum cols [s*64, s*64+64).
__global__ __launch_bounds__(256) void epilogue_kernel(
        const u64* __restrict__ listsg, const float* __restrict__ latent,
        const float* __restrict__ partials, const float* __restrict__ cnt,
        float* __restrict__ out_mask, float* __restrict__ out_idx,
        float* __restrict__ out_imp, float* __restrict__ out_tok,
        float* __restrict__ out_glob) {
    int blk = blockIdx.x;
    int b = blk >> 2, s = blk & 3;
    int t = threadIdx.x, w = t >> 6, l = t & 63;
    __shared__ u64 lb[CH * K];       // 8 KB
    __shared__ u64 wres[4][K];       // 2 KB
    __shared__ int sortedIdx[K];
    __shared__ float redc[4][64];    // 1 KB

    for (int q = 0; q < CH * K / 256; ++q)
        lb[t + 256 * q] = listsg[(size_t)b * CH * K + t + 256 * q];
    __syncthreads();

    // level 1: wave w merges lists [4w, 4w+4)
    {
        u64 cur = lb[(w * 4) * K + l];
        #pragma unroll
        for (int q = 1; q < 4; ++q) {
            u64 rev = lb[(w * 4 + q) * K + (63 - l)];
            cur = (cur > rev) ? cur : rev;
            cur = wave_merge_desc(cur, l);
        }
        wres[w][l] = cur;
    }
    __syncthreads();
    // level 2: wave 0 merges the 4 wave-results
    if (w == 0) {
        u64 cur = wres[0][l];
        #pragma unroll
        for (int q = 1; q < 4; ++q) {
            u64 rev = wres[q][63 - l];
            cur = (cur > rev) ? cur : rev;
            cur = wave_merge_desc(cur, l);
        }
        unsigned int u = (unsigned int)(cur >> 16);
        int pos = 2047 - (int)(cur & 0xFFFFu);
        sortedIdx[l] = pos;
        if (s == 0) {
            unsigned int fu = (u & 0x80000000u) ? (u ^ 0x80000000u) : ~u;
            float selv = __uint_as_float(fu);
            bool m = (u != MASKED_KEY);
            float x = m ? selv : -1e9f;
            float mx = x;
            #pragma unroll
            for (int mm = 1; mm <= 32; mm <<= 1) mx = fmaxf(mx, __shfl_xor(mx, mm, 64));
            float e = expf(x - mx);
            float sm = e;
            #pragma unroll
            for (int mm = 1; mm <= 32; mm <<= 1) sm += __shfl_xor(sm, mm, 64);
            out_idx[b * K + l] = (float)pos;
            out_mask[b * K + l] = m ? 1.f : 0.f;
            out_imp[b * K + l] = e / sm;
        }
    }
    __syncthreads();

    // gather rows [s*16, s*16+16), 4 rows per wave
    #pragma unroll
    for (int rr2 = 0; rr2 < 4; ++rr2) {
        int r = s * 16 + w * 4 + rr2;
        int idx = sortedIdx[r];
        float4 x = ((const float4*)(latent + ((size_t)b * N + idx) * D))[l];
        ((float4*)(out_tok + ((size_t)b * K + r) * D))[l] = x;
    }
    // colsum cols [s*64, s*64+64): 4 threads/col, 4 chunks each
    {
        int c = s * 64 + (t & 63);
        int qd = t >> 6;
        float gs = 0.f;
        #pragma unroll
        for (int q = 0; q < 4; ++q)
            gs += partials[((size_t)b * CH + qd * 4 + q) * D + c];
        redc[qd][t & 63] = gs;
        __syncthreads();
        if (t < 64)
            out_glob[b * D + s * 64 + t] =
                (redc[0][t] + redc[1][t] + redc[2][t] + redc[3][t]) / cnt[b];
    }
}

extern "C" void kernel_launch(void* const* d_in, const int* in_sizes, int n_in,
                              void* d_out, int out_size, void* d_ws, size_t ws_size,
                              hipStream_t stream) {
    const float* latent = (const float*)d_in[0];
    const void*  maskp  = d_in[1];
    const float* Wq = (const float*)d_in[2];
    const float* bq = (const float*)d_in[3];
    const float* Wk = (const float*)d_in[4];
    const float* bk = (const float*)d_in[5];
    const float* Ws = (const float*)d_in[6];
    const float* bs = (const float*)d_in[7];

    float* ws = (float*)d_ws;
    float* v      = ws + OFF_V;
    float* c2     = ws + OFF_C2;
    float* cnt    = ws + OFF_CNT;
    float* part   = ws + OFF_PART;
    int*   modep  = (int*)(ws + OFF_MODE);
    u64*   lists  = (u64*)(ws + OFF_LISTS);
    float* out = (float*)d_out;

    hipLaunchKernelGGL(prep_kernel, dim3(B * 2), dim3(256), 0, stream,
                       latent, maskp, Wq, bq, Wk, bk, Ws, bs, v, c2, cnt, modep);
    hipLaunchKernelGGL(main_kernel, dim3(CH, B), dim3(256), 0, stream,
                       latent, maskp, modep, v, c2, part, lists);
    hipLaunchKernelGGL(epilogue_kernel, dim3(B * 4), dim3(256), 0, stream,
                       lists, latent, part, cnt,
                       out + O_MASK, out + O_IDX, out + O_IMP, out + O_TOK, out + O_GLOB);
}